// Round 12
// baseline (25.249 us; speedup 1.0000x reference)
//
#include <hip/hip_runtime.h>
#include <math.h>

namespace {

typedef float f32x2 __attribute__((ext_vector_type(2)));

constexpr int NLAY = 10;
constexpr int NQB  = 4;
constexpr int NB   = 16;
constexpr int HH   = 128;
constexpr int WW   = 128;
constexpr int DI   = HH - 1;           // 127
constexpr int DJ   = WW - 1;           // 127
constexpr int NPATCH = NB * DI * DJ;   // 258064
constexpr int BLK   = 256;
constexpr int GRID  = (NPATCH + BLK - 1) / BLK;   // 1009

// Combined CZ(0,1)*CZ(2,3)*CZ(1,2) sign per basis index (bit3=a,...,bit0=d)
constexpr unsigned SIGNMASK = 0xB848u;

__device__ __forceinline__ float2 cmul(float2 a, float2 b) {
    return make_float2(fmaf(a.x, b.x, -a.y * b.y), fmaf(a.x, b.y, a.y * b.x));
}
__device__ __forceinline__ float2 cadd(float2 a, float2 b) {
    return make_float2(a.x + b.x, a.y + b.y);
}
__device__ __forceinline__ void mm2(float2* D, const float2* A, const float2* B) {
    D[0] = cadd(cmul(A[0], B[0]), cmul(A[1], B[2]));
    D[1] = cadd(cmul(A[0], B[1]), cmul(A[1], B[3]));
    D[2] = cadd(cmul(A[2], B[0]), cmul(A[3], B[2]));
    D[3] = cadd(cmul(A[2], B[1]), cmul(A[3], B[3]));
}

// hardware trig: v_sin_f32/v_cos_f32 take REVOLUTIONS (D = sin(S0*2pi)).
// sin(pi*t) == hwsin(0.5*t). All args used here are within [-0.25, 0.5].
__device__ __forceinline__ float hwsin(float x) { return __builtin_amdgcn_sinf(x); }
__device__ __forceinline__ float hwcos(float x) { return __builtin_amdgcn_cosf(x); }

// packed complex FMA / MUL with vector operands (validated r5)
__device__ __forceinline__ void cfma_pk(f32x2& acc, f32x2 m, f32x2 s) {
    asm("v_pk_fma_f32 %0, %1, %2, %0 op_sel_hi:[0,1,1]\n\t"
        "v_pk_fma_f32 %0, %1, %2, %0 op_sel:[1,1,0] op_sel_hi:[1,0,1] neg_lo:[1,0,0]"
        : "+v"(acc) : "v"(m), "v"(s));
}
__device__ __forceinline__ f32x2 cmul_pk(f32x2 a, f32x2 b) {
    f32x2 c;
    asm("v_pk_mul_f32 %0, %1, %2 op_sel_hi:[0,1]\n\t"
        "v_pk_fma_f32 %0, %1, %2, %0 op_sel:[1,1,0] op_sel_hi:[1,0,1] neg_lo:[1,0,0]"
        : "=&v"(c) : "v"(a), "v"(b));
    return c;
}
// packed complex FMA with the matrix element in an SGPR PAIR (uniform M)
__device__ __forceinline__ void cfma_pk_s(f32x2& acc, f32x2 m, f32x2 s) {
    asm("v_pk_fma_f32 %0, %1, %2, %0 op_sel_hi:[0,1,1]\n\t"
        "v_pk_fma_f32 %0, %1, %2, %0 op_sel:[1,1,0] op_sel_hi:[1,0,1] neg_lo:[1,0,0]"
        : "+v"(acc) : "s"(m), "v"(s));
}

// ---- K1: butterfly M build, ONE block, writes M[o][j] to global ----
__global__ __launch_bounds__(256) void build_M_kernel(
    const float* __restrict__ gates,    // [10,4,3] one-hot
    const float* __restrict__ angles,   // [10,4]
    float2* __restrict__ M_out)         // [16][16] row-major
{
    __shared__ float4 UgA[NLAY * NQB];   // {U00.re,U00.im,U01.re,U01.im}
    __shared__ float4 UgB[NLAY * NQB];   // {U10.re,U10.im,U11.re,U11.im}

    const int t = threadIdx.x;

    if (t < NLAY * NQB) {
        constexpr float INV4PI = 0.0795774715459477f;   // rad*0.5 -> revolutions
        const float ang = angles[t] * INV4PI;
        const float ax = gates[t * 3 + 0] * ang;
        const float ay = gates[t * 3 + 1] * ang;
        const float az = gates[t * 3 + 2] * ang;
        const float sx = hwsin(ax), cx = hwcos(ax);
        const float sy = hwsin(ay), cy = hwcos(ay);
        const float sz = hwsin(az), cz = hwcos(az);
        float2 RX[4] = {{cx, 0.f}, {0.f, -sx}, {0.f, -sx}, {cx, 0.f}};
        float2 RY[4] = {{cy, 0.f}, {-sy, 0.f}, {sy, 0.f}, {cy, 0.f}};
        float2 RZ[4] = {{cz, -sz}, {0.f, 0.f}, {0.f, 0.f}, {cz, sz}};
        float2 Mt[4], U[4];
        mm2(Mt, RY, RX);
        mm2(U, RZ, Mt);
        UgA[t] = make_float4(U[0].x, U[0].y, U[1].x, U[1].y);
        UgB[t] = make_float4(U[2].x, U[2].y, U[3].x, U[3].y);
    }
    __syncthreads();

    // thread t: amplitude row o = t&15 of basis column j = t>>4 (validated r9)
    const int o = t & 15, j = t >> 4;
    const float czs = ((SIGNMASK >> o) & 1u) ? -1.f : 1.f;

    f32x2 amp = {(o == j) ? 1.f : 0.f, 0.f};
#pragma unroll 1
    for (int l = 0; l < NLAY; ++l) {
#pragma unroll
        for (int q = 0; q < NQB; ++q) {
            const int mask = 8 >> q;
            const float4 uA = UgA[l * 4 + q];
            const float4 uB = UgB[l * 4 + q];
            const bool b = (o & mask) != 0;
            const f32x2 diag = b ? f32x2{uB.z, uB.w} : f32x2{uA.x, uA.y};
            const f32x2 off  = b ? f32x2{uB.x, uB.y} : f32x2{uA.z, uA.w};
            const f32x2 part = {__shfl_xor(amp.x, mask), __shfl_xor(amp.y, mask)};
            f32x2 na = cmul_pk(diag, amp);
            cfma_pk(na, off, part);
            amp = na;
        }
        amp.x *= czs;
        amp.y *= czs;
    }
    M_out[o * 16 + j] = make_float2(amp.x, amp.y);
}

// ---- K2: one patch/thread, M via s_load (SGPR), no LDS, no barriers ----
__global__ __launch_bounds__(256) void qcnn_main_kernel(
    const float* __restrict__ images,   // [16,128,128,3]
    const float* __restrict__ Mflat,    // [16*16*2] floats, never written here
    float* __restrict__ out)            // [16,127,127,4]
{
    const int gid = blockIdx.x * BLK + threadIdx.x;
    const int n = min(gid, NPATCH - 1);
    const int bimg = n / (DI * DJ);
    const int rem  = n - bimg * (DI * DJ);
    const int pi   = rem / DJ;
    const int pj   = rem - pi * DJ;
    const float* base = images + ((size_t)(bimg * HH + pi) * WW + pj) * 3;

    float d[4][3];
#pragma unroll
    for (int a = 0; a < 2; ++a) {
#pragma unroll
        for (int b = 0; b < 2; ++b) {
            const float* px = base + ((size_t)a * WW + b) * 3;
            d[a * 2 + b][0] = px[0];
            d[a * 2 + b][1] = px[1];
            d[a * 2 + b][2] = px[2];
        }
    }

    f32x2 S[NQB][2];
#pragma unroll
    for (int q = 0; q < NQB; ++q) {
        const float d0 = d[q][0], d1 = d[q][1], d2 = d[q][2];
        const float aarg = 0.25f * (d0 + d2);
        const float barg = 0.25f * (d2 - d0);
        const float targ = 0.25f * d1;
        const float sa = hwsin(aarg), ca = hwcos(aarg);
        const float sb = hwsin(barg), cb = hwcos(barg);
        const float stt = hwsin(targ), ctt = hwcos(targ);
        S[q][0] = f32x2{ca * ctt, -sa * ctt};
        S[q][1] = f32x2{cb * stt,  sb * stt};
    }

    f32x2 st[16];
#pragma unroll
    for (int a = 0; a < 2; ++a) {
#pragma unroll
        for (int b = 0; b < 2; ++b) {
            const f32x2 ab = cmul_pk(S[0][a], S[1][b]);
#pragma unroll
            for (int c = 0; c < 2; ++c) {
                const f32x2 abc = cmul_pk(ab, S[2][c]);
#pragma unroll
                for (int dd = 0; dd < 2; ++dd) {
                    st[a * 8 + b * 4 + c * 2 + dd] = cmul_pk(abc, S[3][dd]);
                }
            }
        }
    }

    // matvec: M rows at uniform invariant addresses -> s_load; pk-FMA takes
    // the SGPR pair directly (1 scalar operand per VOP3P instruction).
    const f32x2* Mv = reinterpret_cast<const f32x2*>(Mflat);
    float e0 = 0.f, e1 = 0.f, e2 = 0.f, e3 = 0.f;
#pragma unroll 2
    for (int oo = 0; oo < 16; ++oo) {
        f32x2 acc = {0.f, 0.f};
#pragma unroll
        for (int k = 0; k < 16; ++k) {
            cfma_pk_s(acc, Mv[oo * 16 + k], st[k]);
        }
        const float pr = fmaf(acc.x, acc.x, acc.y * acc.y);
        e0 += (oo & 8) ? -pr : pr;
        e1 += (oo & 4) ? -pr : pr;
        e2 += (oo & 2) ? -pr : pr;
        e3 += (oo & 1) ? -pr : pr;
    }

    if (gid < NPATCH) {
        *reinterpret_cast<float4*>(out + (size_t)n * 4) =
            make_float4(e0, e1, e2, e3);
    }
}

}  // namespace

extern "C" void kernel_launch(void* const* d_in, const int* in_sizes, int n_in,
                              void* d_out, int out_size, void* d_ws, size_t ws_size,
                              hipStream_t stream) {
    const float* images = (const float*)d_in[0];
    const float* gates  = (const float*)d_in[1];
    const float* angles = (const float*)d_in[2];
    float* out = (float*)d_out;
    float2* M = (float2*)d_ws;   // 2048 bytes

    build_M_kernel<<<1, 256, 0, stream>>>(gates, angles, M);
    qcnn_main_kernel<<<GRID, BLK, 0, stream>>>(images, (const float*)M, out);
}

// Round 13
// 18.117 us; speedup vs baseline: 1.3936x; 1.3936x over previous
//
#include <hip/hip_runtime.h>
#include <math.h>

namespace {

typedef float f32x2 __attribute__((ext_vector_type(2)));
typedef float f32x4 __attribute__((ext_vector_type(4)));
typedef short bf16x8 __attribute__((ext_vector_type(8)));
typedef int   i32x4 __attribute__((ext_vector_type(4)));

constexpr int NLAY = 10;
constexpr int NQB  = 4;
constexpr int NB   = 16;
constexpr int HH   = 128;
constexpr int WW   = 128;
constexpr int DI   = HH - 1;           // 127
constexpr int DJ   = WW - 1;           // 127
constexpr int NPATCH = NB * DI * DJ;   // 258064
constexpr int BLK   = 256;
constexpr int GRID  = (NPATCH + BLK - 1) / BLK;   // 1009

constexpr unsigned SIGNMASK = 0xB848u;   // fused CZ signs
constexpr unsigned PSEL = 0x07060302u;   // v_perm: pack high16(b),high16(a)

__device__ __forceinline__ float2 cmul(float2 a, float2 b) {
    return make_float2(fmaf(a.x, b.x, -a.y * b.y), fmaf(a.x, b.y, a.y * b.x));
}
__device__ __forceinline__ float2 cadd(float2 a, float2 b) {
    return make_float2(a.x + b.x, a.y + b.y);
}
__device__ __forceinline__ void mm2(float2* D, const float2* A, const float2* B) {
    D[0] = cadd(cmul(A[0], B[0]), cmul(A[1], B[2]));
    D[1] = cadd(cmul(A[0], B[1]), cmul(A[1], B[3]));
    D[2] = cadd(cmul(A[2], B[0]), cmul(A[3], B[2]));
    D[3] = cadd(cmul(A[2], B[1]), cmul(A[3], B[3]));
}

// hw trig in REVOLUTIONS: sin(pi*t) == hwsin(0.5*t); args within [-0.25, 0.5]
__device__ __forceinline__ float hwsin(float x) { return __builtin_amdgcn_sinf(x); }
__device__ __forceinline__ float hwcos(float x) { return __builtin_amdgcn_cosf(x); }

// packed complex FMA / MUL (validated r5-r10)
__device__ __forceinline__ void cfma_pk(f32x2& acc, f32x2 m, f32x2 s) {
    asm("v_pk_fma_f32 %0, %1, %2, %0 op_sel_hi:[0,1,1]\n\t"
        "v_pk_fma_f32 %0, %1, %2, %0 op_sel:[1,1,0] op_sel_hi:[1,0,1] neg_lo:[1,0,0]"
        : "+v"(acc) : "v"(m), "v"(s));
}
__device__ __forceinline__ f32x2 cmul_pk(f32x2 a, f32x2 b) {
    f32x2 c;
    asm("v_pk_mul_f32 %0, %1, %2 op_sel_hi:[0,1]\n\t"
        "v_pk_fma_f32 %0, %1, %2, %0 op_sel:[1,1,0] op_sel_hi:[1,0,1] neg_lo:[1,0,0]"
        : "=&v"(c) : "v"(a), "v"(b));
    return c;
}

__device__ __forceinline__ unsigned fb(float x) { return __float_as_uint(x); }
__device__ __forceinline__ float trunchi(float x) {
    return __uint_as_float(__float_as_uint(x) & 0xffff0000u);
}
// pack trunc-bf16(lo_val) into low16, trunc-bf16(hi_val) into high16 (validated r6)
__device__ __forceinline__ unsigned pk2(float lo_val, float hi_val) {
    return __builtin_amdgcn_perm(fb(hi_val), fb(lo_val), PSEL);
}

union FragCast { i32x4 i; bf16x8 v; };
__device__ __forceinline__ bf16x8 as_frag(int d0, int d1, int d2, int d3) {
    FragCast f;
    f.i = i32x4{d0, d1, d2, d3};
    return f.v;
}

// ---- ONE fused kernel: butterfly M + 1-patch/thread init + MFMA matvec ----
__global__ __launch_bounds__(256) void qcnn_fused_kernel(
    const float* __restrict__ images,   // [16,128,128,3]
    const float* __restrict__ gates,    // [10,4,3] one-hot
    const float* __restrict__ angles,   // [10,4]
    float* __restrict__ out)            // [16,127,127,4]
{
    __shared__ float4 UgA[NLAY * NQB];   // {U00.re,U00.im,U01.re,U01.im}
    __shared__ float4 UgB[NLAY * NQB];   // {U10.re,U10.im,U11.re,U11.im}
    __shared__ float2 Mf[16][16];        // final circuit unitary M[o][j]
    __shared__ float4 stCh[8][BLK];      // chunk-transposed patch states, 32 KB

    const int t = threadIdx.x;
    const int gid = blockIdx.x * BLK + t;
    const int n = min(gid, NPATCH - 1);

    // ---- issue this thread's 12 pixel loads first (hide under M build) ----
    const int bimg = n / (DI * DJ);
    const int rem  = n - bimg * (DI * DJ);
    const int pi   = rem / DJ;
    const int pj   = rem - pi * DJ;
    const float* base = images + ((size_t)(bimg * HH + pi) * WW + pj) * 3;
    float d[4][3];
#pragma unroll
    for (int a = 0; a < 2; ++a) {
#pragma unroll
        for (int b = 0; b < 2; ++b) {
            const float* px = base + ((size_t)a * WW + b) * 3;
            d[a * 2 + b][0] = px[0];
            d[a * 2 + b][1] = px[1];
            d[a * 2 + b][2] = px[2];
        }
    }

    // ---- phase 1a: 40 lanes build gate unitaries (validated r8/r9) ----
    if (t < NLAY * NQB) {
        constexpr float INV4PI = 0.0795774715459477f;   // rad*0.5 -> revolutions
        const float ang = angles[t] * INV4PI;
        const float ax = gates[t * 3 + 0] * ang;
        const float ay = gates[t * 3 + 1] * ang;
        const float az = gates[t * 3 + 2] * ang;
        const float sx = hwsin(ax), cx = hwcos(ax);
        const float sy = hwsin(ay), cy = hwcos(ay);
        const float sz = hwsin(az), cz = hwcos(az);
        float2 RX[4] = {{cx, 0.f}, {0.f, -sx}, {0.f, -sx}, {cx, 0.f}};
        float2 RY[4] = {{cy, 0.f}, {-sy, 0.f}, {sy, 0.f}, {cy, 0.f}};
        float2 RZ[4] = {{cz, -sz}, {0.f, 0.f}, {0.f, 0.f}, {cz, sz}};
        float2 Mt[4], U[4];
        mm2(Mt, RY, RX);
        mm2(U, RZ, Mt);
        UgA[t] = make_float4(U[0].x, U[0].y, U[1].x, U[1].y);
        UgB[t] = make_float4(U[2].x, U[2].y, U[3].x, U[3].y);
    }
    __syncthreads();

    // ---- phase 1b: butterfly M columns (validated r9) -> Mf ----
    {
        const int o = t & 15, j = t >> 4;
        const float czs = ((SIGNMASK >> o) & 1u) ? -1.f : 1.f;
        f32x2 amp = {(o == j) ? 1.f : 0.f, 0.f};
#pragma unroll 1
        for (int l = 0; l < NLAY; ++l) {
#pragma unroll
            for (int q = 0; q < NQB; ++q) {
                const int mask = 8 >> q;
                const float4 uA = UgA[l * 4 + q];
                const float4 uB = UgB[l * 4 + q];
                const bool bb = (o & mask) != 0;
                const f32x2 diag = bb ? f32x2{uB.z, uB.w} : f32x2{uA.x, uA.y};
                const f32x2 off  = bb ? f32x2{uB.x, uB.y} : f32x2{uA.z, uA.w};
                const f32x2 part = {__shfl_xor(amp.x, mask), __shfl_xor(amp.y, mask)};
                f32x2 na = cmul_pk(diag, amp);
                cfma_pk(na, off, part);
                amp = na;
            }
            amp.x *= czs;
            amp.y *= czs;
        }
        Mf[o][j] = make_float2(amp.x, amp.y);
    }

    // ---- phase 1c: per-patch init (validated r8/r10), write st to LDS ----
    {
        f32x2 S[NQB][2];
#pragma unroll
        for (int q = 0; q < NQB; ++q) {
            const float d0 = d[q][0], d1 = d[q][1], d2 = d[q][2];
            const float aarg = 0.25f * (d0 + d2);
            const float barg = 0.25f * (d2 - d0);
            const float targ = 0.25f * d1;
            const float sa = hwsin(aarg), ca = hwcos(aarg);
            const float sb = hwsin(barg), cb = hwcos(barg);
            const float stt = hwsin(targ), ctt = hwcos(targ);
            S[q][0] = f32x2{ca * ctt, -sa * ctt};
            S[q][1] = f32x2{cb * stt,  sb * stt};
        }
        f32x2 st[16];
#pragma unroll
        for (int a = 0; a < 2; ++a) {
#pragma unroll
            for (int b = 0; b < 2; ++b) {
                const f32x2 ab = cmul_pk(S[0][a], S[1][b]);
#pragma unroll
                for (int c = 0; c < 2; ++c) {
                    const f32x2 abc = cmul_pk(ab, S[2][c]);
#pragma unroll
                    for (int dd = 0; dd < 2; ++dd) {
                        st[a * 8 + b * 4 + c * 2 + dd] = cmul_pk(abc, S[3][dd]);
                    }
                }
            }
        }
        // chunk cc holds st[2cc], st[2cc+1]; coalesced ds_write_b128
#pragma unroll
        for (int cc = 0; cc < 8; ++cc) {
            stCh[cc][t] = make_float4(st[2 * cc].x, st[2 * cc].y,
                                      st[2 * cc + 1].x, st[2 * cc + 1].y);
        }
    }
    __syncthreads();

    // ---- A-fragments from Mf (layout + split validated r6) ----
    const int lane = t & 63;
    const int c16  = lane & 15;     // MFMA col (patch) / A row
    const int qq   = lane >> 4;     // k-quadrant
    bf16x8 Areh, Arel, Aimh, Aiml;
    {
        const float2* Mr = &Mf[c16][4 * qq];
        int areh[4], arel[4], aimh[4], aiml[4];
#pragma unroll
        for (int dd = 0; dd < 4; ++dd) {
            const float2 mv = Mr[dd];
            const float mre = mv.x, mim = mv.y, nim = -mv.y;
            areh[dd] = pk2(mre, nim);
            aimh[dd] = pk2(mim, mre);
            arel[dd] = pk2(mre - trunchi(mre), nim - trunchi(nim));
            aiml[dd] = pk2(mim - trunchi(mim), mre - trunchi(mre));
        }
        Areh = as_frag(areh[0], areh[1], areh[2], areh[3]);
        Arel = as_frag(arel[0], arel[1], arel[2], arel[3]);
        Aimh = as_frag(aimh[0], aimh[1], aimh[2], aimh[3]);
        Aiml = as_frag(aiml[0], aiml[1], aiml[2], aiml[3]);
    }

    // ---- phase 2: 4 groups of 16 patches per wave (pipeline = r6) ----
    const int wbase = (t >> 6) * 64;
    const f32x4 z4 = {0.f, 0.f, 0.f, 0.f};
#pragma unroll
    for (int g = 0; g < 4; ++g) {
        const int P = wbase + g * 16 + c16;           // patch within block
        const float4 lo = stCh[2 * qq][P];            // st[4qq+0..1]
        const float4 hi = stCh[2 * qq + 1][P];        // st[4qq+2..3]

        const int bh0 = pk2(lo.x, lo.y), bh1 = pk2(lo.z, lo.w);
        const int bh2 = pk2(hi.x, hi.y), bh3 = pk2(hi.z, hi.w);
        const int bl0 = pk2(lo.x - trunchi(lo.x), lo.y - trunchi(lo.y));
        const int bl1 = pk2(lo.z - trunchi(lo.z), lo.w - trunchi(lo.w));
        const int bl2 = pk2(hi.x - trunchi(hi.x), hi.y - trunchi(hi.y));
        const int bl3 = pk2(hi.z - trunchi(hi.z), hi.w - trunchi(hi.w));
        const bf16x8 Bh = as_frag(bh0, bh1, bh2, bh3);
        const bf16x8 Bl = as_frag(bl0, bl1, bl2, bl3);

        f32x4 accre = __builtin_amdgcn_mfma_f32_16x16x32_bf16(Areh, Bh, z4, 0, 0, 0);
        f32x4 accim = __builtin_amdgcn_mfma_f32_16x16x32_bf16(Aimh, Bh, z4, 0, 0, 0);
        accre = __builtin_amdgcn_mfma_f32_16x16x32_bf16(Areh, Bl, accre, 0, 0, 0);
        accim = __builtin_amdgcn_mfma_f32_16x16x32_bf16(Aimh, Bl, accim, 0, 0, 0);
        accre = __builtin_amdgcn_mfma_f32_16x16x32_bf16(Arel, Bh, accre, 0, 0, 0);
        accim = __builtin_amdgcn_mfma_f32_16x16x32_bf16(Aiml, Bh, accim, 0, 0, 0);

        // C: col = lane&15 (patch), row oo = 4*qq + reg (validated r6)
        const float pr0 = fmaf(accre[0], accre[0], accim[0] * accim[0]);
        const float pr1 = fmaf(accre[1], accre[1], accim[1] * accim[1]);
        const float pr2 = fmaf(accre[2], accre[2], accim[2] * accim[2]);
        const float pr3 = fmaf(accre[3], accre[3], accim[3] * accim[3]);
        const float a2 = pr0 + pr1, b2 = pr2 + pr3;
        const float c2 = pr0 - pr1, d2 = pr2 - pr3;
        const float s  = a2 + b2;
        float e0 = (qq & 2) ? -s : s;
        float e1 = (qq & 1) ? -s : s;
        float e2 = a2 - b2;
        float e3 = c2 + d2;

        e0 += __shfl_xor(e0, 16); e1 += __shfl_xor(e1, 16);
        e2 += __shfl_xor(e2, 16); e3 += __shfl_xor(e3, 16);
        e0 += __shfl_xor(e0, 32); e1 += __shfl_xor(e1, 32);
        e2 += __shfl_xor(e2, 32); e3 += __shfl_xor(e3, 32);

        const int n_out = blockIdx.x * BLK + P;
        if (qq == 0 && n_out < NPATCH) {
            reinterpret_cast<float4*>(out)[n_out] = make_float4(e0, e1, e2, e3);
        }
    }
}

}  // namespace

extern "C" void kernel_launch(void* const* d_in, const int* in_sizes, int n_in,
                              void* d_out, int out_size, void* d_ws, size_t ws_size,
                              hipStream_t stream) {
    const float* images = (const float*)d_in[0];
    const float* gates  = (const float*)d_in[1];
    const float* angles = (const float*)d_in[2];
    float* out = (float*)d_out;

    qcnn_fused_kernel<<<GRID, BLK, 0, stream>>>(images, gates, angles, out);
}

// Round 14
// 17.327 us; speedup vs baseline: 1.4572x; 1.0456x over previous
//
#include <hip/hip_runtime.h>
#include <math.h>

namespace {

typedef float f32x2 __attribute__((ext_vector_type(2)));

constexpr int NLAY = 10;
constexpr int NQB  = 4;
constexpr int NB   = 16;
constexpr int HH   = 128;
constexpr int WW   = 128;
constexpr int DI   = HH - 1;           // 127
constexpr int DJ   = WW - 1;           // 127
constexpr int NPATCH = NB * DI * DJ;   // 258064
constexpr int PPT   = 4;               // patches per thread
constexpr int BLK   = 256;
constexpr int PER_BLOCK = BLK * PPT;   // 1024
constexpr int GRID  = (NPATCH + PER_BLOCK - 1) / PER_BLOCK;   // 253

// Combined CZ(0,1)*CZ(2,3)*CZ(1,2) sign per basis index (bit3=a,...,bit0=d)
constexpr unsigned SIGNMASK = 0xB848u;

__device__ __forceinline__ float2 cmul(float2 a, float2 b) {
    return make_float2(fmaf(a.x, b.x, -a.y * b.y), fmaf(a.x, b.y, a.y * b.x));
}
__device__ __forceinline__ float2 cadd(float2 a, float2 b) {
    return make_float2(a.x + b.x, a.y + b.y);
}
__device__ __forceinline__ void mm2(float2* D, const float2* A, const float2* B) {
    D[0] = cadd(cmul(A[0], B[0]), cmul(A[1], B[2]));
    D[1] = cadd(cmul(A[0], B[1]), cmul(A[1], B[3]));
    D[2] = cadd(cmul(A[2], B[0]), cmul(A[3], B[2]));
    D[3] = cadd(cmul(A[2], B[1]), cmul(A[3], B[3]));
}

// hw trig in REVOLUTIONS: sin(pi*t) == hwsin(0.5*t); args within [-0.25, 0.5]
__device__ __forceinline__ float hwsin(float x) { return __builtin_amdgcn_sinf(x); }
__device__ __forceinline__ float hwcos(float x) { return __builtin_amdgcn_cosf(x); }

// packed complex FMA: acc.{lo,hi} += {Re,Im} of m*s (validated r5)
__device__ __forceinline__ void cfma_pk(f32x2& acc, f32x2 m, f32x2 s) {
    asm("v_pk_fma_f32 %0, %1, %2, %0 op_sel_hi:[0,1,1]\n\t"
        "v_pk_fma_f32 %0, %1, %2, %0 op_sel:[1,1,0] op_sel_hi:[1,0,1] neg_lo:[1,0,0]"
        : "+v"(acc) : "v"(m), "v"(s));
}

// packed complex multiply: c = a*b (validated r5)
__device__ __forceinline__ f32x2 cmul_pk(f32x2 a, f32x2 b) {
    f32x2 c;
    asm("v_pk_mul_f32 %0, %1, %2 op_sel_hi:[0,1]\n\t"
        "v_pk_fma_f32 %0, %1, %2, %0 op_sel:[1,1,0] op_sel_hi:[1,0,1] neg_lo:[1,0,0]"
        : "=&v"(c) : "v"(a), "v"(b));
    return c;
}

// ---- single fused kernel: butterfly M build (shfl, no barriers) + matvec ----
__global__ __launch_bounds__(256) void qcnn_fused_kernel(
    const float* __restrict__ images,   // [16,128,128,3]
    const float* __restrict__ gates,    // [10,4,3] one-hot
    const float* __restrict__ angles,   // [10,4]
    float* __restrict__ out)            // [16,127,127,4]
{
    __shared__ float4 UgA[NLAY * NQB];   // {U00.re,U00.im,U01.re,U01.im}
    __shared__ float4 UgB[NLAY * NQB];   // {U10.re,U10.im,U11.re,U11.im}
    __shared__ float2 Mf[16][16];        // final M[o][j]

    const int t = threadIdx.x;
    const int n_base = blockIdx.x * PER_BLOCK + t;

    // ---- issue ALL pixel loads first: latency hides under the M build ----
    float d[PPT][4][3];
#pragma unroll
    for (int p = 0; p < PPT; ++p) {
        const int n = min(n_base + p * BLK, NPATCH - 1);
        const int bimg = n / (DI * DJ);
        const int rem  = n - bimg * (DI * DJ);
        const int pi   = rem / DJ;
        const int pj   = rem - pi * DJ;
        const float* base = images + ((size_t)(bimg * HH + pi) * WW + pj) * 3;
#pragma unroll
        for (int a = 0; a < 2; ++a) {
#pragma unroll
            for (int b = 0; b < 2; ++b) {
                const float* px = base + ((size_t)a * WW + b) * 3;
                d[p][a * 2 + b][0] = px[0];
                d[p][a * 2 + b][1] = px[1];
                d[p][a * 2 + b][2] = px[2];
            }
        }
    }

    // ---- phase 1a: 40 lanes build gate unitaries (hw trig, revolutions) ----
    if (t < NLAY * NQB) {
        constexpr float INV4PI = 0.0795774715459477f;   // 1/(4*pi): rad*0.5 -> rev
        const float ang = angles[t] * INV4PI;
        const float ax = gates[t * 3 + 0] * ang;
        const float ay = gates[t * 3 + 1] * ang;
        const float az = gates[t * 3 + 2] * ang;
        const float sx = hwsin(ax), cx = hwcos(ax);
        const float sy = hwsin(ay), cy = hwcos(ay);
        const float sz = hwsin(az), cz = hwcos(az);
        float2 RX[4] = {{cx, 0.f}, {0.f, -sx}, {0.f, -sx}, {cx, 0.f}};
        float2 RY[4] = {{cy, 0.f}, {-sy, 0.f}, {sy, 0.f}, {cy, 0.f}};
        float2 RZ[4] = {{cz, -sz}, {0.f, 0.f}, {0.f, 0.f}, {cz, sz}};
        float2 Mt[4], U[4];
        mm2(Mt, RY, RX);
        mm2(U, RZ, Mt);
        UgA[t] = make_float4(U[0].x, U[0].y, U[1].x, U[1].y);
        UgB[t] = make_float4(U[2].x, U[2].y, U[3].x, U[3].y);
    }
    __syncthreads();

    // ---- phase 1b: butterfly columns through the circuit, shfl-based ----
    // thread t: amplitude row o = t&15 of basis column j = t>>4 (validated r9)
    {
        const int o = t & 15, j = t >> 4;
        const float czs = ((SIGNMASK >> o) & 1u) ? -1.f : 1.f;
        f32x2 amp = {(o == j) ? 1.f : 0.f, 0.f};
#pragma unroll 1
        for (int l = 0; l < NLAY; ++l) {
#pragma unroll
            for (int q = 0; q < NQB; ++q) {
                const int mask = 8 >> q;
                const float4 uA = UgA[l * 4 + q];      // uniform b128 broadcast
                const float4 uB = UgB[l * 4 + q];
                const bool b = (o & mask) != 0;
                const f32x2 diag = b ? f32x2{uB.z, uB.w} : f32x2{uA.x, uA.y};
                const f32x2 off  = b ? f32x2{uB.x, uB.y} : f32x2{uA.z, uA.w};
                const f32x2 part = {__shfl_xor(amp.x, mask), __shfl_xor(amp.y, mask)};
                f32x2 na = cmul_pk(diag, amp);
                cfma_pk(na, off, part);
                amp = na;
            }
            amp.x *= czs;
            amp.y *= czs;
        }
        Mf[o][j] = make_float2(amp.x, amp.y);
    }
    __syncthreads();

    // ---- phase 2: PPT patches per thread, packed-fp32 matvec (r5-r10) ----
    f32x2 st[PPT][16];
#pragma unroll
    for (int p = 0; p < PPT; ++p) {
        f32x2 S[NQB][2];
#pragma unroll
        for (int q = 0; q < NQB; ++q) {
            const float d0 = d[p][q][0], d1 = d[p][q][1], d2 = d[p][q][2];
            const float aarg = 0.25f * (d0 + d2);
            const float barg = 0.25f * (d2 - d0);
            const float targ = 0.25f * d1;
            const float sa = hwsin(aarg), ca = hwcos(aarg);
            const float sb = hwsin(barg), cb = hwcos(barg);
            const float stt = hwsin(targ), ctt = hwcos(targ);
            S[q][0] = f32x2{ca * ctt, -sa * ctt};
            S[q][1] = f32x2{cb * stt,  sb * stt};
        }

#pragma unroll
        for (int a = 0; a < 2; ++a) {
#pragma unroll
            for (int b = 0; b < 2; ++b) {
                const f32x2 ab = cmul_pk(S[0][a], S[1][b]);
#pragma unroll
                for (int c = 0; c < 2; ++c) {
                    const f32x2 abc = cmul_pk(ab, S[2][c]);
#pragma unroll
                    for (int dd = 0; dd < 2; ++dd) {
                        st[p][a * 8 + b * 4 + c * 2 + dd] = cmul_pk(abc, S[3][dd]);
                    }
                }
            }
        }
    }

    float e0[PPT], e1[PPT], e2[PPT], e3[PPT];
#pragma unroll
    for (int p = 0; p < PPT; ++p) { e0[p] = e1[p] = e2[p] = e3[p] = 0.f; }

    const float4* Mrow = reinterpret_cast<const float4*>(&Mf[0][0]);
#pragma unroll 2
    for (int oo = 0; oo < 16; ++oo) {
        float4 m[8];
#pragma unroll
        for (int kk = 0; kk < 8; ++kk) m[kk] = Mrow[oo * 8 + kk];   // broadcasts
#pragma unroll
        for (int p = 0; p < PPT; ++p) {
            f32x2 acc = {0.f, 0.f};
#pragma unroll
            for (int kk = 0; kk < 8; ++kk) {
                cfma_pk(acc, f32x2{m[kk].x, m[kk].y}, st[p][2 * kk]);
                cfma_pk(acc, f32x2{m[kk].z, m[kk].w}, st[p][2 * kk + 1]);
            }
            const float pr = fmaf(acc.x, acc.x, acc.y * acc.y);
            e0[p] += (oo & 8) ? -pr : pr;
            e1[p] += (oo & 4) ? -pr : pr;
            e2[p] += (oo & 2) ? -pr : pr;
            e3[p] += (oo & 1) ? -pr : pr;
        }
    }

#pragma unroll
    for (int p = 0; p < PPT; ++p) {
        const int n = n_base + p * BLK;
        if (n < NPATCH) {
            *reinterpret_cast<float4*>(out + (size_t)n * 4) =
                make_float4(e0[p], e1[p], e2[p], e3[p]);
        }
    }
}

}  // namespace

extern "C" void kernel_launch(void* const* d_in, const int* in_sizes, int n_in,
                              void* d_out, int out_size, void* d_ws, size_t ws_size,
                              hipStream_t stream) {
    const float* images = (const float*)d_in[0];
    const float* gates  = (const float*)d_in[1];
    const float* angles = (const float*)d_in[2];
    float* out = (float*)d_out;

    qcnn_fused_kernel<<<GRID, BLK, 0, stream>>>(images, gates, angles, out);
}